// Round 6
// baseline (432.857 us; speedup 1.0000x reference)
//
#include <hip/hip_runtime.h>
#include <math.h>

#define NN 16
#define FF 192001
#define NFFTN 384000
#define N1F 1024
#define N2F 375
#define TWO_PI 6.283185307179586476925286766559

__constant__ float c_delays[16] = {809.f, 877.f, 937.f, 1049.f, 1151.f, 1249.f, 1373.f, 1499.f,
                                   1617.f, 1753.f, 1879.f, 2003.f, 2131.f, 2269.f, 2393.f, 2521.f};

__device__ __forceinline__ float2 cmulf(float2 a, float2 b) {
  return make_float2(a.x * b.x - a.y * b.y, a.x * b.y + a.y * b.x);
}

// ---------------------------------------------------------------------------
// A = expm(triu(X,1) - triu(X,1)^T) in double via scaling-and-squaring Taylor.
// Writes AG[i][j] = A[i][j] * gamma[j] as float. One block of 256 threads.
// ---------------------------------------------------------------------------
__global__ void expm_kernel(const float* __restrict__ X, float* __restrict__ AGout) {
  __shared__ double S[16][16], P[16][16], E[16][16];
  const int i = threadIdx.x >> 4, j = threadIdx.x & 15;
  double xu = (j > i) ? (double)X[i * 16 + j] : 0.0;
  double xl = (i > j) ? (double)X[j * 16 + i] : 0.0;
  double s = (xu - xl) * (1.0 / 256.0);  // scale by 2^-8
  S[i][j] = s;
  P[i][j] = s;
  E[i][j] = (i == j ? 1.0 : 0.0) + s;
  __syncthreads();
  for (int k = 2; k <= 24; ++k) {
    double acc = 0.0;
#pragma unroll
    for (int l = 0; l < 16; ++l) acc += P[i][l] * S[l][j];
    acc /= (double)k;
    __syncthreads();
    P[i][j] = acc;
    E[i][j] += acc;
    __syncthreads();
  }
  for (int t = 0; t < 8; ++t) {  // 8 squarings
    double acc = 0.0;
#pragma unroll
    for (int l = 0; l < 16; ++l) acc += E[i][l] * E[l][j];
    __syncthreads();
    E[i][j] = acc;
    __syncthreads();
  }
  double g = exp((double)c_delays[j] * log(0.9998));
  AGout[i * 16 + j] = (float)(E[i][j] * g);
}

// ---------------------------------------------------------------------------
// Per-frequency 16x16 complex Gauss-Jordan solve, 16 lanes per frequency.
// LDS layout Mrow[col][tid]: lane-contiguous float2 (conflict-free).
// CPLX=false: writes real(H) as float. CPLX=true: writes interleaved complex.
// ---------------------------------------------------------------------------
template <bool CPLX>
__global__ __launch_bounds__(256) void solve_kernel(
    const float* __restrict__ Bv, const float* __restrict__ Cv,
    const float* __restrict__ AGin, float* __restrict__ Hout,
    float2* __restrict__ G) {
  __shared__ float2 Mrow[17][256];  // [column 0..16(rhs)][thread]
  __shared__ float AG[16][16];
  __shared__ float Cs[16];
  const int tid = threadIdx.x;
  AG[tid >> 4][tid & 15] = AGin[tid];
  if (tid < 16) Cs[tid] = Cv[tid];
  const int grp = tid >> 4;
  const int r = tid & 15;
  const int gbase = grp << 4;
  int f = blockIdx.x * 16 + grp;
  const bool active = (f < FF);
  if (!active) f = FF - 1;
  __syncthreads();

  // Row r of M = diag(e^{i m_r w}) - AG
  double omega = M_PI * (double)f / 192000.0;
  double th = fmod((double)c_delays[r] * omega, TWO_PI);
  float si, co;
  sincosf((float)th, &si, &co);
#pragma unroll
  for (int c = 0; c < 16; ++c) {
    float re = -AG[r][c];
    float im = 0.0f;
    if (c == r) { re += co; im = si; }
    Mrow[c][tid] = make_float2(re, im);
  }
  Mrow[16][tid] = make_float2(Bv[r], 0.0f);
  __syncthreads();

  bool done = false;
  int mycol = 0;
  for (int k = 0; k < 16; ++k) {
    float2 mk = Mrow[k][tid];
    float v = done ? -1.0f : (mk.x * mk.x + mk.y * mk.y);
    int idx = r;
#pragma unroll
    for (int off = 8; off > 0; off >>= 1) {  // argmax over the 16-lane group
      float ov = __shfl_xor(v, off, 16);
      int oi = __shfl_xor(idx, off, 16);
      if (ov > v || (ov == v && oi < idx)) { v = ov; idx = oi; }
    }
    const int p = idx;           // uniform within group
    const int prow = gbase + p;
    float2 pk = Mrow[k][prow];   // broadcast read within group
    float invd = 1.0f / (pk.x * pk.x + pk.y * pk.y);
    float2 rc = make_float2(pk.x * invd, -pk.y * invd);  // 1/pivot
    // Multiplier vs the NORMALIZED pivot row is M[r][k] itself.
    // (Round-5 bug: fk = mk*rc divided by the pivot twice -> garbage.)
    float2 fk = mk;
    const bool ispiv = (r == p);
    for (int c = k + 1; c <= 16; ++c) {
      float2 pc = Mrow[c][prow];       // read before this iteration's write
      float2 pn = cmulf(pc, rc);       // normalized pivot row element
      float2 ov2 = Mrow[c][tid];
      float2 nv;
      if (ispiv)
        nv = pn;
      else
        nv = make_float2(ov2.x - (fk.x * pn.x - fk.y * pn.y),
                         ov2.y - (fk.x * pn.y + fk.y * pn.x));
      Mrow[c][tid] = nv;
    }
    if (ispiv) { done = true; mycol = k; }
    __syncthreads();
  }

  float2 y = Mrow[16][tid];  // solution component for column mycol
  float cc = Cs[mycol];
  float2 h = make_float2(y.x * cc, y.y * cc);
  if (active) {
    if (CPLX) {
      ((float2*)Hout)[(size_t)f * 16 + mycol] = h;
    } else {
      Hout[(size_t)f * 16 + mycol] = h.x;  // real part only
    }
  }
  float sx = h.x, sy = h.y;
#pragma unroll
  for (int off = 8; off > 0; off >>= 1) {
    sx += __shfl_xor(sx, off, 16);
    sy += __shfl_xor(sy, off, 16);
  }
  if (active && r == 0) {
    if (f == 0 || f == 192000) sy = 0.0f;  // c2r ignores DC/Nyquist imag
    G[f] = make_float2(sx, sy);
    if (f > 0 && f < 192000) G[NFFTN - f] = make_float2(sx, -sy);
  }
}

// ---------------------------------------------------------------------------
// Stage A: 375 x (1024-point inverse FFT, Stockham in LDS) + outer twiddle.
// A[k2,t1] = sum_k1 G[k2+375*k1] e^{+2pi i k1 t1/1024};  Bb[t1*375+k2] = A * e^{+2pi i k2 t1/N}
// ---------------------------------------------------------------------------
__global__ __launch_bounds__(256) void fftA_kernel(const float2* __restrict__ G,
                                                   float2* __restrict__ Bb) {
  __shared__ float2 buf[2][1024];
  const int k2 = blockIdx.x;
  const int tid = threadIdx.x;
#pragma unroll
  for (int rr = 0; rr < 4; ++rr) {
    int k1 = tid + 256 * rr;
    buf[0][k1] = G[k2 + 375 * k1];
  }
  __syncthreads();
  int src = 0, nt = 1024, s = 1;
  for (int st = 0; st < 10; ++st) {
    int m = nt >> 1;
#pragma unroll
    for (int rr = 0; rr < 2; ++rr) {
      int jj = tid + 256 * rr;   // butterfly index 0..511
      int p = jj >> st;
      int q = jj & (s - 1);
      float ang = (float)p * (6.28318530717958647692f / (float)nt);
      float ws_, wc_;
      sincosf(ang, &ws_, &wc_);
      float2 a = buf[src][q + s * p];
      float2 b = buf[src][q + s * (p + m)];
      float2 sum = make_float2(a.x + b.x, a.y + b.y);
      float2 d = make_float2(a.x - b.x, a.y - b.y);
      float2 wd = make_float2(d.x * wc_ - d.y * ws_, d.x * ws_ + d.y * wc_);
      buf[src ^ 1][q + s * (2 * p)] = sum;
      buf[src ^ 1][q + s * (2 * p + 1)] = wd;
    }
    __syncthreads();
    src ^= 1;
    nt >>= 1;
    s <<= 1;
  }
  const double tw0 = TWO_PI * (double)k2 / (double)NFFTN;
#pragma unroll
  for (int rr = 0; rr < 4; ++rr) {
    int t1 = tid + 256 * rr;
    float2 vz = buf[src][t1];
    float a = (float)(tw0 * (double)t1);  // k2*t1 < 384000 -> angle < 2pi
    float sn, cs;
    sincosf(a, &sn, &cs);
    Bb[t1 * 375 + k2] = make_float2(vz.x * cs - vz.y * sn, vz.x * sn + vz.y * cs);
  }
}

// ---------------------------------------------------------------------------
// Stage B: per t1, direct 375-point inverse DFT over k2 (real part only).
// h[t1 + 1024*t2] = (1/N) sum_k2 Bb[t1*375+k2] e^{+2pi i k2 t2/375}
// Writes directly into the h region of d_out (pre-normalization).
// ---------------------------------------------------------------------------
__global__ __launch_bounds__(384) void fftB_kernel(const float2* __restrict__ Bb,
                                                   float* __restrict__ hout) {
  __shared__ float2 bv[375];
  __shared__ float2 tw[375];
  const int t1 = blockIdx.x;
  const int tid = threadIdx.x;
  for (int i = tid; i < 375; i += 384) {
    bv[i] = Bb[t1 * 375 + i];
    float ang = (float)(TWO_PI * (double)i / 375.0);
    float s, c;
    sincosf(ang, &s, &c);
    tw[i] = make_float2(c, s);
  }
  __syncthreads();
  const int t2 = tid;
  if (t2 < 375) {
    float acc = 0.0f;
    int idx = 0;
    for (int k2 = 0; k2 < 375; ++k2) {
      float2 b = bv[k2];
      float2 w = tw[idx];
      acc += b.x * w.x - b.y * w.y;
      idx += t2;
      if (idx >= 375) idx -= 375;
    }
    hout[t1 + 1024 * t2] = acc * (1.0f / (float)NFFTN);
  }
}

__global__ void max_kernel(const float* __restrict__ h, unsigned* __restrict__ mx) {
  float m = 0.0f;
  for (int i = blockIdx.x * blockDim.x + threadIdx.x; i < NFFTN;
       i += gridDim.x * blockDim.x)
    m = fmaxf(m, fabsf(h[i]));
#pragma unroll
  for (int off = 32; off > 0; off >>= 1) m = fmaxf(m, __shfl_xor(m, off, 64));
  if ((threadIdx.x & 63) == 0) atomicMax(mx, __float_as_uint(m));  // all values >= 0
}

__global__ void norm_kernel(float* __restrict__ h, const unsigned* __restrict__ mx) {
  int i = blockIdx.x * blockDim.x + threadIdx.x;
  float mv = __uint_as_float(*mx);
  if (i < NFFTN) h[i] = h[i] / mv;
}

extern "C" void kernel_launch(void* const* d_in, const int* in_sizes, int n_in,
                              void* d_out, int out_size, void* d_ws, size_t ws_size,
                              hipStream_t stream) {
  (void)in_sizes; (void)n_in; (void)ws_size;
  const float* Bv = (const float*)d_in[2];
  const float* Cv = (const float*)d_in[3];
  const float* X  = (const float*)d_in[4];
  float* out = (float*)d_out;
  char* ws = (char*)d_ws;
  // ws layout (bytes):
  float2* G    = (float2*)(ws);             // 384000 complex = 3,072,000 B
  float2* Bb   = (float2*)(ws + 3072000);   // 384000 complex = 3,072,000 B
  unsigned* mx = (unsigned*)(ws + 6144000); // 4 B (ws is poisoned 0xAA -> must zero)
  float*  AGw  = (float*)(ws + 6144064);    // 256 floats

  float* htail = out + (out_size - NFFTN);  // h region of d_out

  hipMemsetAsync(mx, 0, 4, stream);
  expm_kernel<<<1, 256, 0, stream>>>(X, AGw);
  // Output-0 layout: real(H) [192001*16] floats (expected, out_size==3,456,016);
  // fallback: interleaved complex64 viewed as float32 (out_size==6,528,032).
  if (out_size >= 2 * FF * NN + NFFTN) {
    solve_kernel<true><<<(FF + 15) / 16, 256, 0, stream>>>(Bv, Cv, AGw, out, G);
  } else {
    solve_kernel<false><<<(FF + 15) / 16, 256, 0, stream>>>(Bv, Cv, AGw, out, G);
  }
  fftA_kernel<<<N2F, 256, 0, stream>>>(G, Bb);
  fftB_kernel<<<N1F, 384, 0, stream>>>(Bb, htail);
  max_kernel<<<256, 256, 0, stream>>>(htail, mx);
  norm_kernel<<<1500, 256, 0, stream>>>(htail, mx);
}

// Round 7
// 306.593 us; speedup vs baseline: 1.4118x; 1.4118x over previous
//
#include <hip/hip_runtime.h>
#include <math.h>

#define NN 16
#define FF 192001
#define NFFTN 384000
#define N1F 1024
#define N2F 375
#define TWO_PI 6.283185307179586476925286766559

__constant__ float c_delays[16] = {809.f, 877.f, 937.f, 1049.f, 1151.f, 1249.f, 1373.f, 1499.f,
                                   1617.f, 1753.f, 1879.f, 2003.f, 2131.f, 2269.f, 2393.f, 2521.f};

__device__ __forceinline__ float2 cmulf(float2 a, float2 b) {
  return make_float2(a.x * b.x - a.y * b.y, a.x * b.y + a.y * b.x);
}

// ---------------------------------------------------------------------------
// A = expm(triu(X,1) - triu(X,1)^T) in double via scaling-and-squaring Taylor.
// Writes AG[i][j] = A[i][j] * gamma[j] as float. One block of 256 threads.
// ---------------------------------------------------------------------------
__global__ void expm_kernel(const float* __restrict__ X, float* __restrict__ AGout) {
  __shared__ double S[16][16], P[16][16], E[16][16];
  const int i = threadIdx.x >> 4, j = threadIdx.x & 15;
  double xu = (j > i) ? (double)X[i * 16 + j] : 0.0;
  double xl = (i > j) ? (double)X[j * 16 + i] : 0.0;
  double s = (xu - xl) * (1.0 / 256.0);  // scale by 2^-8
  S[i][j] = s;
  P[i][j] = s;
  E[i][j] = (i == j ? 1.0 : 0.0) + s;
  __syncthreads();
  for (int k = 2; k <= 24; ++k) {
    double acc = 0.0;
#pragma unroll
    for (int l = 0; l < 16; ++l) acc += P[i][l] * S[l][j];
    acc /= (double)k;
    __syncthreads();
    P[i][j] = acc;
    E[i][j] += acc;
    __syncthreads();
  }
  for (int t = 0; t < 8; ++t) {  // 8 squarings
    double acc = 0.0;
#pragma unroll
    for (int l = 0; l < 16; ++l) acc += E[i][l] * E[l][j];
    __syncthreads();
    E[i][j] = acc;
    __syncthreads();
  }
  double g = exp((double)c_delays[j] * log(0.9998));
  AGout[i * 16 + j] = (float)(E[i][j] * g);
}

// ---------------------------------------------------------------------------
// Per-frequency 16x16 complex Gauss-Jordan solve, 16 lanes per frequency.
// Pivot-free (all leading minors of M = D(I-K), ||K||<=0.851 are
// well-conditioned: sigma_min >= 0.149), row-in-registers, wave-synchronous:
// pivot row broadcast by width-16 shuffles. No barriers, no LDS matrix.
// CPLX=false: writes real(H) as float. CPLX=true: writes interleaved complex.
// ---------------------------------------------------------------------------
template <bool CPLX>
__global__ __launch_bounds__(256) void solve_kernel(
    const float* __restrict__ Bv, const float* __restrict__ Cv,
    const float* __restrict__ AGin, float* __restrict__ Hout,
    float2* __restrict__ G) {
  __shared__ float AGT[16][16];  // transposed: AGT[c][r] = AG[r][c]
  const int tid = threadIdx.x;
  AGT[tid & 15][tid >> 4] = AGin[tid];
  const int r = tid & 15;        // my row
  int f = blockIdx.x * 16 + (tid >> 4);
  const bool active = (f < FF);
  if (!active) f = FF - 1;
  __syncthreads();  // once, for AGT

  // Row r of M = diag(e^{i m_r w}) - AG, kept in registers (+ RHS at [16]).
  double omega = M_PI * (double)f / 192000.0;
  double th = fmod((double)c_delays[r] * omega, TWO_PI);
  float si, co;
  sincosf((float)th, &si, &co);
  float2 reg[17];
#pragma unroll
  for (int c = 0; c < 16; ++c) {
    float re = -AGT[c][r];
    float im = 0.0f;
    if (c == r) { re += co; im = si; }
    reg[c] = make_float2(re, im);
  }
  reg[16] = make_float2(Bv[r], 0.0f);

  // Gauss-Jordan, pivot = row k (no pivoting). Fully unrolled: all reg[]
  // indices compile-time (avoids scratch). Shuffles read lane k's value
  // BEFORE lane k's write in the same iteration (single instruction stream).
#pragma unroll
  for (int k = 0; k < 16; ++k) {
    const float pr = __shfl(reg[k].x, k, 16);
    const float pi_ = __shfl(reg[k].y, k, 16);
    const float invd = 1.0f / (pr * pr + pi_ * pi_);
    const float rcx = pr * invd, rcy = -pi_ * invd;  // 1/pivot
    const float fkx = reg[k].x, fky = reg[k].y;      // my multiplier M[r][k]
    const bool ispiv = (r == k);
#pragma unroll
    for (int c = k + 1; c < 17; ++c) {
      const float pcx = __shfl(reg[c].x, k, 16);
      const float pcy = __shfl(reg[c].y, k, 16);
      const float pnx = pcx * rcx - pcy * rcy;  // normalized pivot row elem
      const float pny = pcx * rcy + pcy * rcx;
      if (ispiv) {
        reg[c].x = pnx;
        reg[c].y = pny;
      } else {
        reg[c].x -= fkx * pnx - fky * pny;
        reg[c].y -= fkx * pny + fky * pnx;
      }
    }
  }

  // reg[16] = x_r of M x = B. H[f][r] = x_r * C[r].
  const float cc = Cv[r];
  float2 h = make_float2(reg[16].x * cc, reg[16].y * cc);
  if (active) {
    if (CPLX) {
      ((float2*)Hout)[(size_t)f * 16 + r] = h;
    } else {
      Hout[(size_t)f * 16 + r] = h.x;  // real part only
    }
  }
  float sx = h.x, sy = h.y;
#pragma unroll
  for (int off = 8; off > 0; off >>= 1) {
    sx += __shfl_xor(sx, off, 16);
    sy += __shfl_xor(sy, off, 16);
  }
  if (active && r == 0) {
    if (f == 0 || f == 192000) sy = 0.0f;  // c2r ignores DC/Nyquist imag
    G[f] = make_float2(sx, sy);
    if (f > 0 && f < 192000) G[NFFTN - f] = make_float2(sx, -sy);
  }
}

// ---------------------------------------------------------------------------
// Stage A: 375 x (1024-point inverse FFT, Stockham in LDS) + outer twiddle.
// A[k2,t1] = sum_k1 G[k2+375*k1] e^{+2pi i k1 t1/1024};  Bb[t1*375+k2] = A * e^{+2pi i k2 t1/N}
// ---------------------------------------------------------------------------
__global__ __launch_bounds__(256) void fftA_kernel(const float2* __restrict__ G,
                                                   float2* __restrict__ Bb) {
  __shared__ float2 buf[2][1024];
  const int k2 = blockIdx.x;
  const int tid = threadIdx.x;
#pragma unroll
  for (int rr = 0; rr < 4; ++rr) {
    int k1 = tid + 256 * rr;
    buf[0][k1] = G[k2 + 375 * k1];
  }
  __syncthreads();
  int src = 0, nt = 1024, s = 1;
  for (int st = 0; st < 10; ++st) {
    int m = nt >> 1;
#pragma unroll
    for (int rr = 0; rr < 2; ++rr) {
      int jj = tid + 256 * rr;   // butterfly index 0..511
      int p = jj >> st;
      int q = jj & (s - 1);
      float ang = (float)p * (6.28318530717958647692f / (float)nt);
      float ws_, wc_;
      sincosf(ang, &ws_, &wc_);
      float2 a = buf[src][q + s * p];
      float2 b = buf[src][q + s * (p + m)];
      float2 sum = make_float2(a.x + b.x, a.y + b.y);
      float2 d = make_float2(a.x - b.x, a.y - b.y);
      float2 wd = make_float2(d.x * wc_ - d.y * ws_, d.x * ws_ + d.y * wc_);
      buf[src ^ 1][q + s * (2 * p)] = sum;
      buf[src ^ 1][q + s * (2 * p + 1)] = wd;
    }
    __syncthreads();
    src ^= 1;
    nt >>= 1;
    s <<= 1;
  }
  const double tw0 = TWO_PI * (double)k2 / (double)NFFTN;
#pragma unroll
  for (int rr = 0; rr < 4; ++rr) {
    int t1 = tid + 256 * rr;
    float2 vz = buf[src][t1];
    float a = (float)(tw0 * (double)t1);  // k2*t1 < 384000 -> angle < 2pi
    float sn, cs;
    sincosf(a, &sn, &cs);
    Bb[t1 * 375 + k2] = make_float2(vz.x * cs - vz.y * sn, vz.x * sn + vz.y * cs);
  }
}

// ---------------------------------------------------------------------------
// Stage B: per t1, direct 375-point inverse DFT over k2 (real part only).
// h[t1 + 1024*t2] = (1/N) sum_k2 Bb[t1*375+k2] e^{+2pi i k2 t2/375}
// Writes directly into the h region of d_out (pre-normalization).
// ---------------------------------------------------------------------------
__global__ __launch_bounds__(384) void fftB_kernel(const float2* __restrict__ Bb,
                                                   float* __restrict__ hout) {
  __shared__ float2 bv[375];
  __shared__ float2 tw[375];
  const int t1 = blockIdx.x;
  const int tid = threadIdx.x;
  for (int i = tid; i < 375; i += 384) {
    bv[i] = Bb[t1 * 375 + i];
    float ang = (float)(TWO_PI * (double)i / 375.0);
    float s, c;
    sincosf(ang, &s, &c);
    tw[i] = make_float2(c, s);
  }
  __syncthreads();
  const int t2 = tid;
  if (t2 < 375) {
    float acc = 0.0f;
    int idx = 0;
    for (int k2 = 0; k2 < 375; ++k2) {
      float2 b = bv[k2];
      float2 w = tw[idx];
      acc += b.x * w.x - b.y * w.y;
      idx += t2;
      if (idx >= 375) idx -= 375;
    }
    hout[t1 + 1024 * t2] = acc * (1.0f / (float)NFFTN);
  }
}

__global__ void max_kernel(const float* __restrict__ h, unsigned* __restrict__ mx) {
  float m = 0.0f;
  for (int i = blockIdx.x * blockDim.x + threadIdx.x; i < NFFTN;
       i += gridDim.x * blockDim.x)
    m = fmaxf(m, fabsf(h[i]));
#pragma unroll
  for (int off = 32; off > 0; off >>= 1) m = fmaxf(m, __shfl_xor(m, off, 64));
  if ((threadIdx.x & 63) == 0) atomicMax(mx, __float_as_uint(m));  // all values >= 0
}

__global__ void norm_kernel(float* __restrict__ h, const unsigned* __restrict__ mx) {
  int i = blockIdx.x * blockDim.x + threadIdx.x;
  float mv = __uint_as_float(*mx);
  if (i < NFFTN) h[i] = h[i] / mv;
}

extern "C" void kernel_launch(void* const* d_in, const int* in_sizes, int n_in,
                              void* d_out, int out_size, void* d_ws, size_t ws_size,
                              hipStream_t stream) {
  (void)in_sizes; (void)n_in; (void)ws_size;
  const float* Bv = (const float*)d_in[2];
  const float* Cv = (const float*)d_in[3];
  const float* X  = (const float*)d_in[4];
  float* out = (float*)d_out;
  char* ws = (char*)d_ws;
  // ws layout (bytes):
  float2* G    = (float2*)(ws);             // 384000 complex = 3,072,000 B
  float2* Bb   = (float2*)(ws + 3072000);   // 384000 complex = 3,072,000 B
  unsigned* mx = (unsigned*)(ws + 6144000); // 4 B (ws is poisoned 0xAA -> must zero)
  float*  AGw  = (float*)(ws + 6144064);    // 256 floats

  float* htail = out + (out_size - NFFTN);  // h region of d_out

  hipMemsetAsync(mx, 0, 4, stream);
  expm_kernel<<<1, 256, 0, stream>>>(X, AGw);
  // Output-0 layout: real(H) [192001*16] floats (expected, out_size==3,456,016);
  // fallback: interleaved complex64 viewed as float32 (out_size==6,528,032).
  if (out_size >= 2 * FF * NN + NFFTN) {
    solve_kernel<true><<<(FF + 15) / 16, 256, 0, stream>>>(Bv, Cv, AGw, out, G);
  } else {
    solve_kernel<false><<<(FF + 15) / 16, 256, 0, stream>>>(Bv, Cv, AGw, out, G);
  }
  fftA_kernel<<<N2F, 256, 0, stream>>>(G, Bb);
  fftB_kernel<<<N1F, 384, 0, stream>>>(Bb, htail);
  max_kernel<<<256, 256, 0, stream>>>(htail, mx);
  norm_kernel<<<1500, 256, 0, stream>>>(htail, mx);
}

// Round 9
// 191.149 us; speedup vs baseline: 2.2645x; 1.6040x over previous
//
#include <hip/hip_runtime.h>
#include <math.h>

#define NN 16
#define FF 192001
#define NFFTN 384000
#define N1F 1024
#define N2F 375
#define TWO_PI 6.283185307179586476925286766559

__constant__ float c_delays[16] = {809.f, 877.f, 937.f, 1049.f, 1151.f, 1249.f, 1373.f, 1499.f,
                                   1617.f, 1753.f, 1879.f, 2003.f, 2131.f, 2269.f, 2393.f, 2521.f};
__constant__ int c_idelays[16] = {809, 877, 937, 1049, 1151, 1249, 1373, 1499,
                                  1617, 1753, 1879, 2003, 2131, 2269, 2393, 2521};

__device__ __forceinline__ float fastrcp(float x) {
#if __has_builtin(__builtin_amdgcn_rcpf)
  return __builtin_amdgcn_rcpf(x);
#else
  return 1.0f / x;
#endif
}

// ---------------------------------------------------------------------------
// A = expm(triu(X,1) - triu(X,1)^T) in double via scaling-and-squaring Taylor.
// Writes AG[i][j] = A[i][j] * gamma[j] as float. One block of 256 threads.
// ---------------------------------------------------------------------------
__global__ void expm_kernel(const float* __restrict__ X, float* __restrict__ AGout) {
  __shared__ double S[16][16], P[16][16], E[16][16];
  const int i = threadIdx.x >> 4, j = threadIdx.x & 15;
  double xu = (j > i) ? (double)X[i * 16 + j] : 0.0;
  double xl = (i > j) ? (double)X[j * 16 + i] : 0.0;
  double s = (xu - xl) * (1.0 / 256.0);  // scale by 2^-8
  S[i][j] = s;
  P[i][j] = s;
  E[i][j] = (i == j ? 1.0 : 0.0) + s;
  __syncthreads();
  for (int k = 2; k <= 24; ++k) {
    double acc = 0.0;
#pragma unroll
    for (int l = 0; l < 16; ++l) acc += P[i][l] * S[l][j];
    acc /= (double)k;
    __syncthreads();
    P[i][j] = acc;
    E[i][j] += acc;
    __syncthreads();
  }
  for (int t = 0; t < 8; ++t) {  // 8 squarings
    double acc = 0.0;
#pragma unroll
    for (int l = 0; l < 16; ++l) acc += E[i][l] * E[l][j];
    __syncthreads();
    E[i][j] = acc;
    __syncthreads();
  }
  double g = exp((double)c_delays[j] * log(0.9998));
  AGout[i * 16 + j] = (float)(E[i][j] * g);
}

// ---------------------------------------------------------------------------
// Width-16 broadcast of lane K via ds_swizzle imm pattern (no addr VGPRs):
// dst lane i reads lane (i & 0x10) | K within each 32-lane group == shfl(v,K,16).
// ---------------------------------------------------------------------------
template <int K>
__device__ __forceinline__ float2 bc16(float2 v) {
  float2 o;
  o.x = __int_as_float(__builtin_amdgcn_ds_swizzle(__float_as_int(v.x), (K << 5) | 0x10));
  o.y = __int_as_float(__builtin_amdgcn_ds_swizzle(__float_as_int(v.y), (K << 5) | 0x10));
  return o;
}

// One pivot-free Gauss-Jordan step; fused multiplier frc = ispiv?(1-rc):M[r][K]*rc
// so the inner loop is a single complex FMA per column.
template <int K>
__device__ __forceinline__ void gj_step(float2 (&reg)[17], const int r) {
  float2 pk = bc16<K>(reg[K]);
  float invd = fastrcp(pk.x * pk.x + pk.y * pk.y);
  float rcx = pk.x * invd, rcy = -pk.y * invd;  // 1/pivot
  const bool ispiv = (r == K);
  float frx = ispiv ? (1.0f - rcx) : (reg[K].x * rcx - reg[K].y * rcy);
  float fry = ispiv ? (-rcy) : (reg[K].x * rcy + reg[K].y * rcx);
#pragma unroll
  for (int c = K + 1; c < 17; ++c) {
    float2 pc = bc16<K>(reg[c]);
    reg[c].x -= frx * pc.x - fry * pc.y;
    reg[c].y -= frx * pc.y + fry * pc.x;
  }
}

template <int K>
struct GJAll {
  static __device__ __forceinline__ void run(float2 (&reg)[17], int r) {
    gj_step<K>(reg, r);
    GJAll<K + 1>::run(reg, r);
  }
};
template <>
struct GJAll<16> {
  static __device__ __forceinline__ void run(float2 (&)[17], int) {}
};

// ---------------------------------------------------------------------------
// Per-frequency 16x16 complex solve, 16 lanes per frequency, rows in VGPRs.
// Pivot-free is safe: M = D(I-K), ||K|| <= 0.9998^809 = 0.851 -> all leading
// minors have sigma_min >= 0.149. launch_bounds(.,6) gives ~85 VGPRs: no spill.
// ---------------------------------------------------------------------------
template <bool CPLX>
__global__ __launch_bounds__(256, 6) void solve_kernel(
    const float* __restrict__ Bv, const float* __restrict__ Cv,
    const float* __restrict__ AGin, float* __restrict__ Hout,
    float2* __restrict__ G) {
  __shared__ float AGp[16][17];  // padded row-major (17: bank-conflict-free)
  __shared__ float Bs[16], Cs[16];
  const int tid = threadIdx.x;
  AGp[tid >> 4][tid & 15] = AGin[tid];
  if (tid < 16) { Bs[tid] = Bv[tid]; Cs[tid] = Cv[tid]; }
  const int r = tid & 15;  // my row
  int f = blockIdx.x * 16 + (tid >> 4);
  const bool active = (f < FF);
  if (!active) f = FF - 1;
  __syncthreads();

  // Exact integer phase: theta = 2pi/384000 * ((m_r * f) mod 384000)
  int ph = (c_idelays[r] * f) % NFFTN;  // m*f <= 2521*192000 < 2^31
  float th = (float)ph * (float)(TWO_PI / (double)NFFTN);
  float si, co;
  sincosf(th, &si, &co);

  float2 reg[17];
#pragma unroll
  for (int c = 0; c < 16; ++c) {
    float re = -AGp[r][c];
    float im = 0.0f;
    if (c == r) { re += co; im = si; }  // compile-time index, cndmask per c
    reg[c] = make_float2(re, im);
  }
  reg[16] = make_float2(Bs[r], 0.0f);

  GJAll<0>::run(reg, r);  // reg[16] = x_r of M x = B

  const float cc = Cs[r];
  float2 h = make_float2(reg[16].x * cc, reg[16].y * cc);
  if (active) {
    if (CPLX) {
      ((float2*)Hout)[(size_t)f * 16 + r] = h;
    } else {
      Hout[(size_t)f * 16 + r] = h.x;  // real part only
    }
  }
  float sx = h.x, sy = h.y;
#pragma unroll
  for (int off = 8; off > 0; off >>= 1) {
    sx += __shfl_xor(sx, off, 16);
    sy += __shfl_xor(sy, off, 16);
  }
  if (active && r == 0) {
    if (f == 0 || f == 192000) sy = 0.0f;  // c2r ignores DC/Nyquist imag
    G[f] = make_float2(sx, sy);
    if (f > 0 && f < 192000) G[NFFTN - f] = make_float2(sx, -sy);
  }
}

// ---------------------------------------------------------------------------
// Stage A: 375 x (1024-point inverse FFT, Stockham in LDS) + outer twiddle.
// ---------------------------------------------------------------------------
__global__ __launch_bounds__(256) void fftA_kernel(const float2* __restrict__ G,
                                                   float2* __restrict__ Bb) {
  __shared__ float2 buf[2][1024];
  const int k2 = blockIdx.x;
  const int tid = threadIdx.x;
#pragma unroll
  for (int rr = 0; rr < 4; ++rr) {
    int k1 = tid + 256 * rr;
    buf[0][k1] = G[k2 + 375 * k1];
  }
  __syncthreads();
  int src = 0, nt = 1024, s = 1;
  for (int st = 0; st < 10; ++st) {
    int m = nt >> 1;
#pragma unroll
    for (int rr = 0; rr < 2; ++rr) {
      int jj = tid + 256 * rr;   // butterfly index 0..511
      int p = jj >> st;
      int q = jj & (s - 1);
      float ang = (float)p * (6.28318530717958647692f / (float)nt);
      float ws_, wc_;
      sincosf(ang, &ws_, &wc_);
      float2 a = buf[src][q + s * p];
      float2 b = buf[src][q + s * (p + m)];
      float2 sum = make_float2(a.x + b.x, a.y + b.y);
      float2 d = make_float2(a.x - b.x, a.y - b.y);
      float2 wd = make_float2(d.x * wc_ - d.y * ws_, d.x * ws_ + d.y * wc_);
      buf[src ^ 1][q + s * (2 * p)] = sum;
      buf[src ^ 1][q + s * (2 * p + 1)] = wd;
    }
    __syncthreads();
    src ^= 1;
    nt >>= 1;
    s <<= 1;
  }
  const double tw0 = TWO_PI * (double)k2 / (double)NFFTN;
#pragma unroll
  for (int rr = 0; rr < 4; ++rr) {
    int t1 = tid + 256 * rr;
    float2 vz = buf[src][t1];
    float a = (float)(tw0 * (double)t1);
    float sn, cs;
    sincosf(a, &sn, &cs);
    Bb[t1 * 375 + k2] = make_float2(vz.x * cs - vz.y * sn, vz.x * sn + vz.y * cs);
  }
}

// ---------------------------------------------------------------------------
// Stage B: per t1, 375-point inverse DFT, mixed-radix 375 = 25x15 (two LDS
// stages, ~15000 cmul vs 140625 direct). Real part only, written to d_out.
// out[t] = sum_a w^{a t} * Y[a][t mod 15],  Y[a][u] = sum_b X[a+25b] e^{2pi i b u/15}
// ---------------------------------------------------------------------------
__global__ __launch_bounds__(384) void fftB_kernel(const float2* __restrict__ Bb,
                                                   float* __restrict__ hout) {
  __shared__ float2 bv[375];
  __shared__ float2 tw[375];      // w^i, w = e^{+2pi i/375}
  __shared__ float2 Y[375];       // Y[a*15 + u]
  const int t1 = blockIdx.x;
  const int tid = threadIdx.x;
  if (tid < 375) {
    bv[tid] = Bb[t1 * 375 + tid];
    float ang = (float)(TWO_PI * (double)tid / 375.0);
    float s, c;
    sincosf(ang, &s, &c);
    tw[tid] = make_float2(c, s);
  }
  __syncthreads();
  if (tid < 375) {
    // stage 1: 25 x 15-point DFTs. j = a*15 + u
    const int a = tid / 15, u = tid - 15 * a;
    float ax = 0.f, ay = 0.f;
    int i15 = 0;  // (b*u) mod 15
#pragma unroll
    for (int b = 0; b < 15; ++b) {
      float2 x = bv[a + 25 * b];
      float2 w = tw[i15 * 25];  // e^{2pi i b u/15}
      ax += x.x * w.x - x.y * w.y;
      ay += x.x * w.y + x.y * w.x;
      i15 += u;
      if (i15 >= 15) i15 -= 15;
    }
    Y[tid] = make_float2(ax, ay);
  }
  __syncthreads();
  if (tid < 375) {
    // stage 2: out[t] = Re( sum_a Y[a][t%15] * w^{a t} )
    const int t = tid;
    const int u = t % 15;
    float acc = 0.f;
    int idx = 0;  // (a*t) mod 375
#pragma unroll
    for (int a = 0; a < 25; ++a) {
      float2 y = Y[a * 15 + u];
      float2 w = tw[idx];
      acc += y.x * w.x - y.y * w.y;
      idx += t;
      if (idx >= 375) idx -= 375;
    }
    hout[t1 + 1024 * t] = acc * (1.0f / (float)NFFTN);
  }
}

__global__ void max_kernel(const float* __restrict__ h, unsigned* __restrict__ mx) {
  float m = 0.0f;
  for (int i = blockIdx.x * blockDim.x + threadIdx.x; i < NFFTN;
       i += gridDim.x * blockDim.x)
    m = fmaxf(m, fabsf(h[i]));
#pragma unroll
  for (int off = 32; off > 0; off >>= 1) m = fmaxf(m, __shfl_xor(m, off, 64));
  if ((threadIdx.x & 63) == 0) atomicMax(mx, __float_as_uint(m));  // all values >= 0
}

__global__ void norm_kernel(float* __restrict__ h, const unsigned* __restrict__ mx) {
  int i = blockIdx.x * blockDim.x + threadIdx.x;
  float mv = __uint_as_float(*mx);
  if (i < NFFTN) h[i] = h[i] / mv;
}

extern "C" void kernel_launch(void* const* d_in, const int* in_sizes, int n_in,
                              void* d_out, int out_size, void* d_ws, size_t ws_size,
                              hipStream_t stream) {
  (void)in_sizes; (void)n_in; (void)ws_size;
  const float* Bv = (const float*)d_in[2];
  const float* Cv = (const float*)d_in[3];
  const float* X  = (const float*)d_in[4];
  float* out = (float*)d_out;
  char* ws = (char*)d_ws;
  float2* G    = (float2*)(ws);             // 384000 complex = 3,072,000 B
  float2* Bb   = (float2*)(ws + 3072000);   // 384000 complex = 3,072,000 B
  unsigned* mx = (unsigned*)(ws + 6144000); // 4 B (ws is poisoned 0xAA -> must zero)
  float*  AGw  = (float*)(ws + 6144064);    // 256 floats

  float* htail = out + (out_size - NFFTN);  // h region of d_out

  hipMemsetAsync(mx, 0, 4, stream);
  expm_kernel<<<1, 256, 0, stream>>>(X, AGw);
  if (out_size >= 2 * FF * NN + NFFTN) {
    solve_kernel<true><<<(FF + 15) / 16, 256, 0, stream>>>(Bv, Cv, AGw, out, G);
  } else {
    solve_kernel<false><<<(FF + 15) / 16, 256, 0, stream>>>(Bv, Cv, AGw, out, G);
  }
  fftA_kernel<<<N2F, 256, 0, stream>>>(G, Bb);
  fftB_kernel<<<N1F, 384, 0, stream>>>(Bb, htail);
  max_kernel<<<256, 256, 0, stream>>>(htail, mx);
  norm_kernel<<<1500, 256, 0, stream>>>(htail, mx);
}

// Round 10
// 166.099 us; speedup vs baseline: 2.6060x; 1.1508x over previous
//
#include <hip/hip_runtime.h>
#include <math.h>

#define NN 16
#define FF 192001
#define NFFTN 384000
#define N1F 1024
#define N2F 375
#define TWO_PI 6.283185307179586476925286766559

__constant__ float c_delays[16] = {809.f, 877.f, 937.f, 1049.f, 1151.f, 1249.f, 1373.f, 1499.f,
                                   1617.f, 1753.f, 1879.f, 2003.f, 2131.f, 2269.f, 2393.f, 2521.f};
__constant__ int c_idelays[16] = {809, 877, 937, 1049, 1151, 1249, 1373, 1499,
                                  1617, 1753, 1879, 2003, 2131, 2269, 2393, 2521};

typedef float v2f __attribute__((ext_vector_type(2)));

__device__ __forceinline__ float fastrcp(float x) {
#if __has_builtin(__builtin_amdgcn_rcpf)
  return __builtin_amdgcn_rcpf(x);
#else
  return 1.0f / x;
#endif
}

// ---------------------------------------------------------------------------
// A = expm(triu(X,1) - triu(X,1)^T) in double via scaling-and-squaring Taylor.
// Writes AG[i][j] = A[i][j]*gamma[j]. Also zeroes the global-max slot (ws is
// poisoned 0xAA before every timed call). One block of 256 threads.
// ---------------------------------------------------------------------------
__global__ void expm_kernel(const float* __restrict__ X, float* __restrict__ AGout,
                            unsigned* __restrict__ mx) {
  if (threadIdx.x == 0) *mx = 0u;
  __shared__ double S[16][16], P[16][16], E[16][16];
  const int i = threadIdx.x >> 4, j = threadIdx.x & 15;
  double xu = (j > i) ? (double)X[i * 16 + j] : 0.0;
  double xl = (i > j) ? (double)X[j * 16 + i] : 0.0;
  double s = (xu - xl) * (1.0 / 256.0);  // scale by 2^-8
  S[i][j] = s;
  P[i][j] = s;
  E[i][j] = (i == j ? 1.0 : 0.0) + s;
  __syncthreads();
  for (int k = 2; k <= 24; ++k) {
    double acc = 0.0;
#pragma unroll
    for (int l = 0; l < 16; ++l) acc += P[i][l] * S[l][j];
    acc /= (double)k;
    __syncthreads();
    P[i][j] = acc;
    E[i][j] += acc;
    __syncthreads();
  }
  for (int t = 0; t < 8; ++t) {  // 8 squarings
    double acc = 0.0;
#pragma unroll
    for (int l = 0; l < 16; ++l) acc += E[i][l] * E[l][j];
    __syncthreads();
    E[i][j] = acc;
    __syncthreads();
  }
  double g = exp((double)c_delays[j] * log(0.9998));
  AGout[i * 16 + j] = (float)(E[i][j] * g);
}

// ---------------------------------------------------------------------------
// Broadcast lane S within 8-lane groups via ds_swizzle imm pattern:
// j = (i & 0x18) | S  (BitMode offset = (S<<5) | 0x18).
// ---------------------------------------------------------------------------
template <int S>
__device__ __forceinline__ v2f bc8(v2f v) {
  v2f o;
  o[0] = __int_as_float(__builtin_amdgcn_ds_swizzle(__float_as_int(v[0]), (S << 5) | 0x18));
  o[1] = __int_as_float(__builtin_amdgcn_ds_swizzle(__float_as_int(v[1]), (S << 5) | 0x18));
  return o;
}

// Column loop of GJ step K: one broadcast serves BOTH owned rows.
template <int K, int C>
struct ColLoop {
  static __device__ __forceinline__ void run(v2f (&A)[17], v2f (&B)[17],
                                             v2f nA0, v2f A1, v2f nB0, v2f B1) {
    v2f pc;
    if constexpr (K & 1) pc = bc8<(K >> 1)>(B[C]);
    else                 pc = bc8<(K >> 1)>(A[C]);
    v2f pcs = {pc[1], pc[0]};
    A[C] = __builtin_elementwise_fma(nA0, pc, A[C]);
    A[C] = __builtin_elementwise_fma(A1, pcs, A[C]);
    B[C] = __builtin_elementwise_fma(nB0, pc, B[C]);
    B[C] = __builtin_elementwise_fma(B1, pcs, B[C]);
    ColLoop<K, C + 1>::run(A, B, nA0, A1, nB0, B1);
  }
};
template <int K>
struct ColLoop<K, 17> {
  static __device__ __forceinline__ void run(v2f (&)[17], v2f (&)[17], v2f, v2f, v2f, v2f) {}
};

// Pivot-free GJ step K (pivot row K owned by lane K>>1, array A if K even else B).
// Fused multiplier fr = ispiv ? (1 - 1/piv) : M[row][K] * (1/piv); update is
// reg[c] -= fr (x) pc, done as two packed-f32 FMAs.
template <int K>
struct GJStep8 {
  static __device__ __forceinline__ void run(v2f (&A)[17], v2f (&B)[17], int s) {
    constexpr int S = K >> 1;
    v2f pk;
    if constexpr (K & 1) pk = bc8<S>(B[K]);
    else                 pk = bc8<S>(A[K]);
    float invd = fastrcp(pk[0] * pk[0] + pk[1] * pk[1]);
    float rcx = pk[0] * invd, rcy = -pk[1] * invd;  // 1/pivot
    bool ispA, ispB;
    if constexpr (K & 1) { ispA = false; ispB = (s == S); }
    else                 { ispA = (s == S); ispB = false; }
    v2f mA = A[K], mB = B[K];
    float frAx = ispA ? (1.0f - rcx) : (mA[0] * rcx - mA[1] * rcy);
    float frAy = ispA ? (-rcy)       : (mA[0] * rcy + mA[1] * rcx);
    float frBx = ispB ? (1.0f - rcx) : (mB[0] * rcx - mB[1] * rcy);
    float frBy = ispB ? (-rcy)       : (mB[0] * rcy + mB[1] * rcx);
    v2f nA0 = {-frAx, -frAx}, A1 = {frAy, -frAy};
    v2f nB0 = {-frBx, -frBx}, B1 = {frBy, -frBy};
    ColLoop<K, K + 1>::run(A, B, nA0, A1, nB0, B1);
    GJStep8<K + 1>::run(A, B, s);
  }
};
template <>
struct GJStep8<16> {
  static __device__ __forceinline__ void run(v2f (&)[17], v2f (&)[17], int) {}
};

// ---------------------------------------------------------------------------
// Per-frequency 16x16 complex solve: 8 lanes/frequency, 2 rows/lane, rows in
// VGPRs. Pivot-free is safe: M = D(I-K), ||K|| <= 0.9998^809 = 0.851 -> all
// leading minors have sigma_min >= 0.149. One ds_swizzle broadcast per column
// feeds both rows; complex FMA as 2 packed-f32 FMAs.
// ---------------------------------------------------------------------------
template <bool CPLX>
__global__ __launch_bounds__(256, 4) void solve_kernel(
    const float* __restrict__ Bv, const float* __restrict__ Cv,
    const float* __restrict__ AGin, float* __restrict__ Hout,
    float2* __restrict__ G) {
  __shared__ float AGp[16][17];
  __shared__ float Bs[16], Cs[16];
  const int tid = threadIdx.x;
  AGp[tid >> 4][tid & 15] = AGin[tid];
  if (tid < 16) { Bs[tid] = Bv[tid]; Cs[tid] = Cv[tid]; }
  const int s = tid & 7;           // sub-index within the 8-lane group
  const int a = 2 * s, b = a + 1;  // my two rows
  int f = blockIdx.x * 32 + (tid >> 3);
  const bool active = (f < FF);
  if (!active) f = FF - 1;
  __syncthreads();

  // Exact integer phases for both rows.
  int pa = (c_idelays[a] * f) % NFFTN;
  int pb = (c_idelays[b] * f) % NFFTN;
  float tha = (float)pa * (float)(TWO_PI / (double)NFFTN);
  float thb = (float)pb * (float)(TWO_PI / (double)NFFTN);
  float sa, ca, sb, cb;
  sincosf(tha, &sa, &ca);
  sincosf(thb, &sb, &cb);

  v2f A[17], B[17];
#pragma unroll
  for (int c = 0; c < 16; ++c) {
    float reA = -AGp[a][c], imA = 0.0f;
    float reB = -AGp[b][c], imB = 0.0f;
    if ((c & 1) == 0) {            // diag of row a possible only at even c
      if (c == a) { reA += ca; imA = sa; }
    } else {                       // diag of row b only at odd c
      if (c == b) { reB += cb; imB = sb; }
    }
    A[c] = (v2f){reA, imA};
    B[c] = (v2f){reB, imB};
  }
  A[16] = (v2f){Bs[a], 0.0f};
  B[16] = (v2f){Bs[b], 0.0f};

  GJStep8<0>::run(A, B, s);  // A[16], B[16] = x_a, x_b of M x = B

  const float cca = Cs[a], ccb = Cs[b];
  v2f hA = {A[16][0] * cca, A[16][1] * cca};
  v2f hB = {B[16][0] * ccb, B[16][1] * ccb};
  if (active) {
    if (CPLX) {
      ((float2*)Hout)[(size_t)f * 16 + a] = make_float2(hA[0], hA[1]);
      ((float2*)Hout)[(size_t)f * 16 + b] = make_float2(hB[0], hB[1]);
    } else {
      *(float2*)&Hout[(size_t)f * 16 + a] = make_float2(hA[0], hB[0]);
    }
  }
  float sx = hA[0] + hB[0], sy = hA[1] + hB[1];
#pragma unroll
  for (int off = 4; off > 0; off >>= 1) {
    sx += __shfl_xor(sx, off, 8);
    sy += __shfl_xor(sy, off, 8);
  }
  if (active && s == 0) {
    if (f == 0 || f == 192000) sy = 0.0f;  // c2r ignores DC/Nyquist imag
    G[f] = make_float2(sx, sy);
    if (f > 0 && f < 192000) G[NFFTN - f] = make_float2(sx, -sy);
  }
}

// ---------------------------------------------------------------------------
// Stage A: 375 x (1024-point inverse FFT, Stockham in LDS) + outer twiddle.
// ---------------------------------------------------------------------------
__global__ __launch_bounds__(256) void fftA_kernel(const float2* __restrict__ G,
                                                   float2* __restrict__ Bb) {
  __shared__ float2 buf[2][1024];
  const int k2 = blockIdx.x;
  const int tid = threadIdx.x;
#pragma unroll
  for (int rr = 0; rr < 4; ++rr) {
    int k1 = tid + 256 * rr;
    buf[0][k1] = G[k2 + 375 * k1];
  }
  __syncthreads();
  int src = 0, nt = 1024, s = 1;
  for (int st = 0; st < 10; ++st) {
    int m = nt >> 1;
#pragma unroll
    for (int rr = 0; rr < 2; ++rr) {
      int jj = tid + 256 * rr;   // butterfly index 0..511
      int p = jj >> st;
      int q = jj & (s - 1);
      float ang = (float)p * (6.28318530717958647692f / (float)nt);
      float ws_, wc_;
      sincosf(ang, &ws_, &wc_);
      float2 a = buf[src][q + s * p];
      float2 b = buf[src][q + s * (p + m)];
      float2 sum = make_float2(a.x + b.x, a.y + b.y);
      float2 d = make_float2(a.x - b.x, a.y - b.y);
      float2 wd = make_float2(d.x * wc_ - d.y * ws_, d.x * ws_ + d.y * wc_);
      buf[src ^ 1][q + s * (2 * p)] = sum;
      buf[src ^ 1][q + s * (2 * p + 1)] = wd;
    }
    __syncthreads();
    src ^= 1;
    nt >>= 1;
    s <<= 1;
  }
  const double tw0 = TWO_PI * (double)k2 / (double)NFFTN;
#pragma unroll
  for (int rr = 0; rr < 4; ++rr) {
    int t1 = tid + 256 * rr;
    float2 vz = buf[src][t1];
    float a = (float)(tw0 * (double)t1);
    float sn, cs;
    sincosf(a, &sn, &cs);
    Bb[t1 * 375 + k2] = make_float2(vz.x * cs - vz.y * sn, vz.x * sn + vz.y * cs);
  }
}

// ---------------------------------------------------------------------------
// Stage B: per t1, 375-point inverse DFT, mixed-radix 375 = 25x15, real part
// written to d_out. Fused block-level |h| max -> one atomicMax per block.
// ---------------------------------------------------------------------------
__global__ __launch_bounds__(384) void fftB_kernel(const float2* __restrict__ Bb,
                                                   float* __restrict__ hout,
                                                   unsigned* __restrict__ mx) {
  __shared__ float2 bv[375];
  __shared__ float2 tw[375];      // w^i, w = e^{+2pi i/375}
  __shared__ float2 Y[375];       // Y[a*15 + u]
  __shared__ float wmax[6];
  const int t1 = blockIdx.x;
  const int tid = threadIdx.x;
  if (tid < 375) {
    bv[tid] = Bb[t1 * 375 + tid];
    float ang = (float)(TWO_PI * (double)tid / 375.0);
    float s, c;
    sincosf(ang, &s, &c);
    tw[tid] = make_float2(c, s);
  }
  __syncthreads();
  if (tid < 375) {
    // stage 1: 25 x 15-point DFTs. j = a*15 + u
    const int a = tid / 15, u = tid - 15 * a;
    float ax = 0.f, ay = 0.f;
    int i15 = 0;  // (b*u) mod 15
#pragma unroll
    for (int b = 0; b < 15; ++b) {
      float2 x = bv[a + 25 * b];
      float2 w = tw[i15 * 25];  // e^{2pi i b u/15}
      ax += x.x * w.x - x.y * w.y;
      ay += x.x * w.y + x.y * w.x;
      i15 += u;
      if (i15 >= 15) i15 -= 15;
    }
    Y[tid] = make_float2(ax, ay);
  }
  __syncthreads();
  float m = 0.0f;
  if (tid < 375) {
    // stage 2: out[t] = Re( sum_a Y[a][t%15] * w^{a t} )
    const int t = tid;
    const int u = t % 15;
    float acc = 0.f;
    int idx = 0;  // (a*t) mod 375
#pragma unroll
    for (int a = 0; a < 25; ++a) {
      float2 y = Y[a * 15 + u];
      float2 w = tw[idx];
      acc += y.x * w.x - y.y * w.y;
      idx += t;
      if (idx >= 375) idx -= 375;
    }
    float hv = acc * (1.0f / (float)NFFTN);
    hout[t1 + 1024 * t] = hv;
    m = fabsf(hv);
  }
  // block max -> one atomic
#pragma unroll
  for (int off = 32; off > 0; off >>= 1) m = fmaxf(m, __shfl_xor(m, off, 64));
  if ((tid & 63) == 0) wmax[tid >> 6] = m;
  __syncthreads();
  if (tid == 0) {
    float mm = wmax[0];
#pragma unroll
    for (int w = 1; w < 6; ++w) mm = fmaxf(mm, wmax[w]);
    atomicMax(mx, __float_as_uint(mm));  // h values: float_as_uint monotone for >=0
  }
}

__global__ void norm_kernel(float* __restrict__ h, const unsigned* __restrict__ mx) {
  int i = blockIdx.x * blockDim.x + threadIdx.x;
  float mv = __uint_as_float(*mx);
  if (i < NFFTN) h[i] = h[i] / mv;
}

extern "C" void kernel_launch(void* const* d_in, const int* in_sizes, int n_in,
                              void* d_out, int out_size, void* d_ws, size_t ws_size,
                              hipStream_t stream) {
  (void)in_sizes; (void)n_in; (void)ws_size;
  const float* Bv = (const float*)d_in[2];
  const float* Cv = (const float*)d_in[3];
  const float* X  = (const float*)d_in[4];
  float* out = (float*)d_out;
  char* ws = (char*)d_ws;
  float2* G    = (float2*)(ws);             // 384000 complex = 3,072,000 B
  float2* Bb   = (float2*)(ws + 3072000);   // 384000 complex = 3,072,000 B
  unsigned* mx = (unsigned*)(ws + 6144000); // 4 B (zeroed by expm_kernel)
  float*  AGw  = (float*)(ws + 6144064);    // 256 floats

  float* htail = out + (out_size - NFFTN);  // h region of d_out

  expm_kernel<<<1, 256, 0, stream>>>(X, AGw, mx);
  if (out_size >= 2 * FF * NN + NFFTN) {
    solve_kernel<true><<<(FF + 31) / 32, 256, 0, stream>>>(Bv, Cv, AGw, out, G);
  } else {
    solve_kernel<false><<<(FF + 31) / 32, 256, 0, stream>>>(Bv, Cv, AGw, out, G);
  }
  fftA_kernel<<<N2F, 256, 0, stream>>>(G, Bb);
  fftB_kernel<<<N1F, 384, 0, stream>>>(Bb, htail, mx);
  norm_kernel<<<1500, 256, 0, stream>>>(htail, mx);
}

// Round 13
// 155.676 us; speedup vs baseline: 2.7805x; 1.0670x over previous
//
#include <hip/hip_runtime.h>
#include <math.h>

#define NN 16
#define FF 192001
#define NFFTN 384000
#define N1F 1024
#define N2F 375
#define TWO_PI 6.283185307179586476925286766559

__constant__ float c_delays[16] = {809.f, 877.f, 937.f, 1049.f, 1151.f, 1249.f, 1373.f, 1499.f,
                                   1617.f, 1753.f, 1879.f, 2003.f, 2131.f, 2269.f, 2393.f, 2521.f};
__constant__ int c_idelays[16] = {809, 877, 937, 1049, 1151, 1249, 1373, 1499,
                                  1617, 1753, 1879, 2003, 2131, 2269, 2393, 2521};

typedef float v2f __attribute__((ext_vector_type(2)));

__device__ __forceinline__ float fastrcp(float x) {
#if __has_builtin(__builtin_amdgcn_rcpf)
  return __builtin_amdgcn_rcpf(x);
#else
  return 1.0f / x;
#endif
}

__device__ __forceinline__ float2 cmulf(float2 a, float2 b) {
  return make_float2(a.x * b.x - a.y * b.y, a.x * b.y + a.y * b.x);
}

// ---------------------------------------------------------------------------
// A = expm(skew(X)) in double (scaling-squaring Taylor); AG = A*diag(gamma).
// Also zeroes the global-max slot (ws is re-poisoned before every call).
// ---------------------------------------------------------------------------
__global__ void expm_kernel(const float* __restrict__ X, float* __restrict__ AGout,
                            unsigned* __restrict__ mx) {
  if (threadIdx.x == 0) *mx = 0u;
  __shared__ double S[16][16], P[16][16], E[16][16];
  const int i = threadIdx.x >> 4, j = threadIdx.x & 15;
  double xu = (j > i) ? (double)X[i * 16 + j] : 0.0;
  double xl = (i > j) ? (double)X[j * 16 + i] : 0.0;
  double s = (xu - xl) * (1.0 / 256.0);
  S[i][j] = s;
  P[i][j] = s;
  E[i][j] = (i == j ? 1.0 : 0.0) + s;
  __syncthreads();
  for (int k = 2; k <= 24; ++k) {
    double acc = 0.0;
#pragma unroll
    for (int l = 0; l < 16; ++l) acc += P[i][l] * S[l][j];
    acc /= (double)k;
    __syncthreads();
    P[i][j] = acc;
    E[i][j] += acc;
    __syncthreads();
  }
  for (int t = 0; t < 8; ++t) {
    double acc = 0.0;
#pragma unroll
    for (int l = 0; l < 16; ++l) acc += E[i][l] * E[l][j];
    __syncthreads();
    E[i][j] = acc;
    __syncthreads();
  }
  double g = exp((double)c_delays[j] * log(0.9998));
  AGout[i * 16 + j] = (float)(E[i][j] * g);
}

// ---------------------------------------------------------------------------
// Broadcast lane S within 4-lane groups: j = (i & 0x1C) | S.
// ---------------------------------------------------------------------------
template <int S>
__device__ __forceinline__ v2f bc4(v2f v) {
  v2f o;
  o[0] = __int_as_float(__builtin_amdgcn_ds_swizzle(__float_as_int(v[0]), (S << 5) | 0x1C));
  o[1] = __int_as_float(__builtin_amdgcn_ds_swizzle(__float_as_int(v[1]), (S << 5) | 0x1C));
  return o;
}

// Column loop of GJ step K: one broadcast feeds FOUR owned rows.
template <int K, int C>
struct ColLoop4 {
  static __device__ __forceinline__ void run(
      v2f (&M0)[17], v2f (&M1)[17], v2f (&M2)[17], v2f (&M3)[17],
      v2f f0a, v2f f0b, v2f f1a, v2f f1b, v2f f2a, v2f f2b, v2f f3a, v2f f3b) {
    constexpr int SL = K & 3, S = K >> 2;
    v2f pc;
    if constexpr (SL == 0) pc = bc4<S>(M0[C]);
    else if constexpr (SL == 1) pc = bc4<S>(M1[C]);
    else if constexpr (SL == 2) pc = bc4<S>(M2[C]);
    else pc = bc4<S>(M3[C]);
    v2f pcs = {pc[1], pc[0]};
    M0[C] = __builtin_elementwise_fma(f0a, pc, M0[C]);
    M0[C] = __builtin_elementwise_fma(f0b, pcs, M0[C]);
    M1[C] = __builtin_elementwise_fma(f1a, pc, M1[C]);
    M1[C] = __builtin_elementwise_fma(f1b, pcs, M1[C]);
    M2[C] = __builtin_elementwise_fma(f2a, pc, M2[C]);
    M2[C] = __builtin_elementwise_fma(f2b, pcs, M2[C]);
    M3[C] = __builtin_elementwise_fma(f3a, pc, M3[C]);
    M3[C] = __builtin_elementwise_fma(f3b, pcs, M3[C]);
    ColLoop4<K, C + 1>::run(M0, M1, M2, M3, f0a, f0b, f1a, f1b, f2a, f2b, f3a, f3b);
  }
};
template <int K>
struct ColLoop4<K, 17> {
  static __device__ __forceinline__ void run(v2f (&)[17], v2f (&)[17], v2f (&)[17], v2f (&)[17],
                                             v2f, v2f, v2f, v2f, v2f, v2f, v2f, v2f) {}
};

// Pivot-free GJ step K. Pivot row K lives in lane K>>2, slot K&3.
// Fused multiplier fr = ispiv ? (1 - 1/piv) : M[row][K]*(1/piv);
// update M[c] -= fr (x) pc_raw  (pivot row ends normalized).
template <int K>
struct GJStep4 {
  static __device__ __forceinline__ void run(v2f (&M0)[17], v2f (&M1)[17], v2f (&M2)[17],
                                             v2f (&M3)[17], int s) {
    constexpr int SL = K & 3, S = K >> 2;
    v2f pk;
    if constexpr (SL == 0) pk = bc4<S>(M0[K]);
    else if constexpr (SL == 1) pk = bc4<S>(M1[K]);
    else if constexpr (SL == 2) pk = bc4<S>(M2[K]);
    else pk = bc4<S>(M3[K]);
    float invd = fastrcp(pk[0] * pk[0] + pk[1] * pk[1]);
    float rcx = pk[0] * invd, rcy = -pk[1] * invd;
    const bool inS = (s == S);
    v2f m0 = M0[K], m1 = M1[K], m2 = M2[K], m3 = M3[K];
    const bool p0 = inS && (SL == 0), p1 = inS && (SL == 1);
    const bool p2 = inS && (SL == 2), p3 = inS && (SL == 3);
    float f0x = p0 ? (1.0f - rcx) : (m0[0] * rcx - m0[1] * rcy);
    float f0y = p0 ? (-rcy)       : (m0[0] * rcy + m0[1] * rcx);
    float f1x = p1 ? (1.0f - rcx) : (m1[0] * rcx - m1[1] * rcy);
    float f1y = p1 ? (-rcy)       : (m1[0] * rcy + m1[1] * rcx);
    float f2x = p2 ? (1.0f - rcx) : (m2[0] * rcx - m2[1] * rcy);
    float f2y = p2 ? (-rcy)       : (m2[0] * rcy + m2[1] * rcx);
    float f3x = p3 ? (1.0f - rcx) : (m3[0] * rcx - m3[1] * rcy);
    float f3y = p3 ? (-rcy)       : (m3[0] * rcy + m3[1] * rcx);
    ColLoop4<K, K + 1>::run(M0, M1, M2, M3,
                            (v2f){-f0x, -f0x}, (v2f){f0y, -f0y},
                            (v2f){-f1x, -f1x}, (v2f){f1y, -f1y},
                            (v2f){-f2x, -f2x}, (v2f){f2y, -f2y},
                            (v2f){-f3x, -f3x}, (v2f){f3y, -f3y});
    GJStep4<K + 1>::run(M0, M1, M2, M3, s);
  }
};
template <>
struct GJStep4<16> {
  static __device__ __forceinline__ void run(v2f (&)[17], v2f (&)[17], v2f (&)[17], v2f (&)[17], int) {}
};

// ---------------------------------------------------------------------------
// Per-frequency 16x16 complex solve: 4 lanes/freq, 4 rows/lane, rows in VGPRs.
// Pivot-free safe: M = D(I-K), ||K|| <= 0.851 -> all leading minors
// sigma_min >= 0.149. One broadcast per column feeds 4 row-updates.
// ---------------------------------------------------------------------------
#define INITROW(Mj, jj, cj, sj)                                                   \
  do {                                                                            \
    const int rr_ = a0 + jj;                                                      \
    float4 q0 = AG4[rr_ * 4 + 0], q1 = AG4[rr_ * 4 + 1];                          \
    float4 q2 = AG4[rr_ * 4 + 2], q3 = AG4[rr_ * 4 + 3];                          \
    Mj[0]  = (v2f){(rr_ == 0  ? cj : 0.0f) - q0.x, (rr_ == 0  ? sj : 0.0f)};      \
    Mj[1]  = (v2f){(rr_ == 1  ? cj : 0.0f) - q0.y, (rr_ == 1  ? sj : 0.0f)};      \
    Mj[2]  = (v2f){(rr_ == 2  ? cj : 0.0f) - q0.z, (rr_ == 2  ? sj : 0.0f)};      \
    Mj[3]  = (v2f){(rr_ == 3  ? cj : 0.0f) - q0.w, (rr_ == 3  ? sj : 0.0f)};      \
    Mj[4]  = (v2f){(rr_ == 4  ? cj : 0.0f) - q1.x, (rr_ == 4  ? sj : 0.0f)};      \
    Mj[5]  = (v2f){(rr_ == 5  ? cj : 0.0f) - q1.y, (rr_ == 5  ? sj : 0.0f)};      \
    Mj[6]  = (v2f){(rr_ == 6  ? cj : 0.0f) - q1.z, (rr_ == 6  ? sj : 0.0f)};      \
    Mj[7]  = (v2f){(rr_ == 7  ? cj : 0.0f) - q1.w, (rr_ == 7  ? sj : 0.0f)};      \
    Mj[8]  = (v2f){(rr_ == 8  ? cj : 0.0f) - q2.x, (rr_ == 8  ? sj : 0.0f)};      \
    Mj[9]  = (v2f){(rr_ == 9  ? cj : 0.0f) - q2.y, (rr_ == 9  ? sj : 0.0f)};      \
    Mj[10] = (v2f){(rr_ == 10 ? cj : 0.0f) - q2.z, (rr_ == 10 ? sj : 0.0f)};      \
    Mj[11] = (v2f){(rr_ == 11 ? cj : 0.0f) - q2.w, (rr_ == 11 ? sj : 0.0f)};      \
    Mj[12] = (v2f){(rr_ == 12 ? cj : 0.0f) - q3.x, (rr_ == 12 ? sj : 0.0f)};      \
    Mj[13] = (v2f){(rr_ == 13 ? cj : 0.0f) - q3.y, (rr_ == 13 ? sj : 0.0f)};      \
    Mj[14] = (v2f){(rr_ == 14 ? cj : 0.0f) - q3.z, (rr_ == 14 ? sj : 0.0f)};      \
    Mj[15] = (v2f){(rr_ == 15 ? cj : 0.0f) - q3.w, (rr_ == 15 ? sj : 0.0f)};      \
    Mj[16] = (v2f){Bs[rr_], 0.0f};                                                \
  } while (0)

template <bool CPLX>
__global__ __launch_bounds__(256, 2) void solve_kernel(
    const float* __restrict__ Bv, const float* __restrict__ Cv,
    const float* __restrict__ AGin, float* __restrict__ Hout,
    float2* __restrict__ G) {
  __shared__ float AGs[16][16];
  __shared__ float Bs[16], Cs[16];
  const int tid = threadIdx.x;
  AGs[tid >> 4][tid & 15] = AGin[tid];
  if (tid < 16) { Bs[tid] = Bv[tid]; Cs[tid] = Cv[tid]; }
  const int s = tid & 3;
  const int a0 = s << 2;  // my 4 rows: a0..a0+3
  int f = blockIdx.x * 64 + (tid >> 2);
  const bool active = (f < FF);
  if (!active) f = FF - 1;
  __syncthreads();

  // Exact integer phases for the 4 rows.
  int ph0 = (c_idelays[a0 + 0] * f) % NFFTN;
  int ph1 = (c_idelays[a0 + 1] * f) % NFFTN;
  int ph2 = (c_idelays[a0 + 2] * f) % NFFTN;
  int ph3 = (c_idelays[a0 + 3] * f) % NFFTN;
  const float k2r = (float)(TWO_PI / (double)NFFTN);
  float c0, s0, c1, s1, c2, s2, c3, s3;
  sincosf((float)ph0 * k2r, &s0, &c0);
  sincosf((float)ph1 * k2r, &s1, &c1);
  sincosf((float)ph2 * k2r, &s2, &c2);
  sincosf((float)ph3 * k2r, &s3, &c3);

  const float4* AG4 = (const float4*)&AGs[0][0];
  v2f M0[17], M1[17], M2[17], M3[17];
  INITROW(M0, 0, c0, s0);
  INITROW(M1, 1, c1, s1);
  INITROW(M2, 2, c2, s2);
  INITROW(M3, 3, c3, s3);

  GJStep4<0>::run(M0, M1, M2, M3, s);  // M*[16] = solution components

  const float cc0 = Cs[a0 + 0], cc1 = Cs[a0 + 1], cc2 = Cs[a0 + 2], cc3 = Cs[a0 + 3];
  v2f h0 = {M0[16][0] * cc0, M0[16][1] * cc0};
  v2f h1 = {M1[16][0] * cc1, M1[16][1] * cc1};
  v2f h2 = {M2[16][0] * cc2, M2[16][1] * cc2};
  v2f h3 = {M3[16][0] * cc3, M3[16][1] * cc3};
  if (active) {
    if (CPLX) {
      float4* dst = (float4*)((float2*)Hout + (size_t)f * 16 + a0);
      dst[0] = (float4){h0[0], h0[1], h1[0], h1[1]};
      dst[1] = (float4){h2[0], h2[1], h3[0], h3[1]};
    } else {
      *(float4*)&Hout[(size_t)f * 16 + a0] = (float4){h0[0], h1[0], h2[0], h3[0]};
    }
  }
  float sx = h0[0] + h1[0] + h2[0] + h3[0];
  float sy = h0[1] + h1[1] + h2[1] + h3[1];
  sx += __shfl_xor(sx, 1, 4); sy += __shfl_xor(sy, 1, 4);
  sx += __shfl_xor(sx, 2, 4); sy += __shfl_xor(sy, 2, 4);
  if (active && s == 0) {
    if (f == 0 || f == 192000) sy = 0.0f;  // c2r ignores DC/Nyquist imag
    G[f] = make_float2(sx, sy);
    if (f > 0 && f < 192000) G[NFFTN - f] = make_float2(sx, -sy);
  }
}

// ---------------------------------------------------------------------------
// T1: GT[k2*1024 + k1] = G[k2 + 375*k1]; LDS 32x32 tiles, both sides coalesced.
// ---------------------------------------------------------------------------
__global__ __launch_bounds__(256) void t1_kernel(const float2* __restrict__ G,
                                                 float2* __restrict__ GT) {
  __shared__ float2 tile[32][33];
  const int k1b = blockIdx.x * 32, k2b = blockIdx.y * 32;
  const int tx = threadIdx.x & 31, ty = threadIdx.x >> 5;
#pragma unroll
  for (int i = 0; i < 4; ++i) {
    int k1 = k1b + ty + 8 * i;
    int k2 = k2b + tx;
    if (k2 < N2F) tile[ty + 8 * i][tx] = G[k2 + N2F * k1];
  }
  __syncthreads();
#pragma unroll
  for (int i = 0; i < 4; ++i) {
    int k2 = k2b + ty + 8 * i;
    int k1 = k1b + tx;
    if (k2 < N2F) GT[k2 * 1024 + k1] = tile[tx][ty + 8 * i];
  }
}

// ---------------------------------------------------------------------------
// Stage A: per k2, 1024-point inverse FFT (Stockham, LDS) + outer twiddle.
// Coalesced read GT[k2*1024+k1]; coalesced write AT[k2*1024+t1].
// Twiddles from LDS tables (no per-butterfly sincosf).
// ---------------------------------------------------------------------------
__global__ __launch_bounds__(256) void fftA_kernel(const float2* __restrict__ GT,
                                                   float2* __restrict__ AT) {
  __shared__ float2 buf[2][1024];
  __shared__ float2 wtab[512];
  __shared__ float2 wA[32], wB[32];
  const int k2 = blockIdx.x;
  const int tid = threadIdx.x;
#pragma unroll
  for (int rr = 0; rr < 4; ++rr) {
    int k1 = tid + 256 * rr;
    buf[0][k1] = GT[k2 * 1024 + k1];
  }
  {
    float s_, c_;
    sincosf((float)tid * (float)(TWO_PI / 1024.0), &s_, &c_);
    wtab[tid] = make_float2(c_, s_);
    sincosf((float)(tid + 256) * (float)(TWO_PI / 1024.0), &s_, &c_);
    wtab[tid + 256] = make_float2(c_, s_);
  }
  if (tid < 64) {
    double base = TWO_PI * (double)k2 / (double)NFFTN;
    float s_, c_;
    if (tid < 32) {
      sincosf((float)(base * (double)tid), &s_, &c_);
      wA[tid] = make_float2(c_, s_);
    } else {
      int j = tid - 32;
      sincosf((float)(base * 32.0 * (double)j), &s_, &c_);
      wB[j] = make_float2(c_, s_);
    }
  }
  __syncthreads();
  int src = 0;
#pragma unroll
  for (int st = 0; st < 10; ++st) {
    const int sS = 1 << st;
    const int m = 512 >> st;
#pragma unroll
    for (int rr2 = 0; rr2 < 2; ++rr2) {
      int jj = tid + 256 * rr2;
      int p = jj >> st;
      int q = jj & (sS - 1);
      float2 w = wtab[p << st];
      float2 a = buf[src][q + sS * p];
      float2 b = buf[src][q + sS * (p + m)];
      float2 sum = make_float2(a.x + b.x, a.y + b.y);
      float2 d = make_float2(a.x - b.x, a.y - b.y);
      float2 wd = make_float2(d.x * w.x - d.y * w.y, d.x * w.y + d.y * w.x);
      buf[src ^ 1][q + sS * (2 * p)] = sum;
      buf[src ^ 1][q + sS * (2 * p + 1)] = wd;
    }
    __syncthreads();
    src ^= 1;
  }
#pragma unroll
  for (int rr = 0; rr < 4; ++rr) {
    int t1 = tid + 256 * rr;
    float2 vz = buf[src][t1];
    float2 tw = cmulf(wA[t1 & 31], wB[t1 >> 5]);
    AT[k2 * 1024 + t1] = cmulf(vz, tw);
  }
}

// ---------------------------------------------------------------------------
// T2: Bb[t1*375 + k2] = AT[k2*1024 + t1]; LDS 32x32 tiles, both sides coalesced.
// ---------------------------------------------------------------------------
__global__ __launch_bounds__(256) void t2_kernel(const float2* __restrict__ AT,
                                                 float2* __restrict__ Bb) {
  __shared__ float2 tile[32][33];
  const int t1b = blockIdx.x * 32, k2b = blockIdx.y * 32;
  const int tx = threadIdx.x & 31, ty = threadIdx.x >> 5;
#pragma unroll
  for (int i = 0; i < 4; ++i) {
    int k2 = k2b + ty + 8 * i;
    int t1 = t1b + tx;
    if (k2 < N2F) tile[ty + 8 * i][tx] = AT[k2 * 1024 + t1];
  }
  __syncthreads();
#pragma unroll
  for (int i = 0; i < 4; ++i) {
    int t1 = t1b + ty + 8 * i;
    int k2 = k2b + tx;
    if (k2 < N2F) Bb[t1 * N2F + k2] = tile[tx][ty + 8 * i];
  }
}

// ---------------------------------------------------------------------------
// Stage B: per t1, 375-point inverse DFT (25x15 mixed radix), real part to
// d_out, fused block |h| max -> one atomicMax.
// ---------------------------------------------------------------------------
__global__ __launch_bounds__(384) void fftB_kernel(const float2* __restrict__ Bb,
                                                   float* __restrict__ hout,
                                                   unsigned* __restrict__ mx) {
  __shared__ float2 bv[375];
  __shared__ float2 tw[375];
  __shared__ float2 Y[375];
  __shared__ float wmax[6];
  const int t1 = blockIdx.x;
  const int tid = threadIdx.x;
  if (tid < 375) {
    bv[tid] = Bb[t1 * N2F + tid];
    float ang = (float)(TWO_PI * (double)tid / 375.0);
    float s, c;
    sincosf(ang, &s, &c);
    tw[tid] = make_float2(c, s);
  }
  __syncthreads();
  if (tid < 375) {
    const int a = tid / 15, u = tid - 15 * a;
    float ax = 0.f, ay = 0.f;
    int i15 = 0;
#pragma unroll
    for (int b = 0; b < 15; ++b) {
      float2 x = bv[a + 25 * b];
      float2 w = tw[i15 * 25];
      ax += x.x * w.x - x.y * w.y;
      ay += x.x * w.y + x.y * w.x;
      i15 += u;
      if (i15 >= 15) i15 -= 15;
    }
    Y[tid] = make_float2(ax, ay);
  }
  __syncthreads();
  float m = 0.0f;
  if (tid < 375) {
    const int t = tid;
    const int u = t % 15;
    float acc = 0.f;
    int idx = 0;
#pragma unroll
    for (int a = 0; a < 25; ++a) {
      float2 y = Y[a * 15 + u];
      float2 w = tw[idx];
      acc += y.x * w.x - y.y * w.y;
      idx += t;
      if (idx >= 375) idx -= 375;
    }
    float hv = acc * (1.0f / (float)NFFTN);
    hout[t1 + 1024 * t] = hv;
    m = fabsf(hv);
  }
#pragma unroll
  for (int off = 32; off > 0; off >>= 1) m = fmaxf(m, __shfl_xor(m, off, 64));
  if ((tid & 63) == 0) wmax[tid >> 6] = m;
  __syncthreads();
  if (tid == 0) {
    float mm = wmax[0];
#pragma unroll
    for (int w = 1; w < 6; ++w) mm = fmaxf(mm, wmax[w]);
    atomicMax(mx, __float_as_uint(mm));
  }
}

__global__ void norm_kernel(float* __restrict__ h, const unsigned* __restrict__ mx) {
  int i = blockIdx.x * blockDim.x + threadIdx.x;
  float mv = __uint_as_float(*mx);
  if (i < NFFTN) h[i] = h[i] / mv;
}

extern "C" void kernel_launch(void* const* d_in, const int* in_sizes, int n_in,
                              void* d_out, int out_size, void* d_ws, size_t ws_size,
                              hipStream_t stream) {
  (void)in_sizes; (void)n_in; (void)ws_size;
  const float* Bv = (const float*)d_in[2];
  const float* Cv = (const float*)d_in[3];
  const float* X  = (const float*)d_in[4];
  float* out = (float*)d_out;
  char* ws = (char*)d_ws;
  float2* buf0 = (float2*)(ws);             // G, then AT
  float2* buf1 = (float2*)(ws + 3072000);   // GT, then Bb
  unsigned* mx = (unsigned*)(ws + 6144000); // zeroed by expm_kernel
  float*  AGw  = (float*)(ws + 6144064);

  float* htail = out + (out_size - NFFTN);

  expm_kernel<<<1, 256, 0, stream>>>(X, AGw, mx);
  if (out_size >= 2 * FF * NN + NFFTN) {
    solve_kernel<true><<<(FF + 63) / 64, 256, 0, stream>>>(Bv, Cv, AGw, out, buf0);
  } else {
    solve_kernel<false><<<(FF + 63) / 64, 256, 0, stream>>>(Bv, Cv, AGw, out, buf0);
  }
  t1_kernel<<<dim3(32, 12), 256, 0, stream>>>(buf0, buf1);
  fftA_kernel<<<N2F, 256, 0, stream>>>(buf1, buf0);
  t2_kernel<<<dim3(32, 12), 256, 0, stream>>>(buf0, buf1);
  fftB_kernel<<<N1F, 384, 0, stream>>>(buf1, htail, mx);
  norm_kernel<<<1500, 256, 0, stream>>>(htail, mx);
}